// Round 5
// baseline (750.876 us; speedup 1.0000x reference)
//
#include <hip/hip_runtime.h>
#include <stdint.h>

#define T_TOK 8192
#define DDIM 1024
#define NEXP 8
#define HDIM 3072

typedef __attribute__((ext_vector_type(8))) short bfrag;   // 8 bf16 in 4 VGPRs
typedef __attribute__((ext_vector_type(4))) float facc;    // 4 fp32 acc

// async global->LDS, 16B per lane; LDS dest must be wave-uniform base (+lane*16)
__device__ __forceinline__ void gload16(const void* g, void* l) {
  __builtin_amdgcn_global_load_lds(
      (const __attribute__((address_space(1))) void*)g,
      (__attribute__((address_space(3))) void*)l, 16, 0, 0);
}

__device__ __forceinline__ unsigned short f2bf(float f) {
  unsigned int u = __float_as_uint(f);
  u += 0x7FFFu + ((u >> 16) & 1u);      // round-to-nearest-even
  return (unsigned short)(u >> 16);
}

// ---------------- gating: one wave per token (+ fused x->bf16 convert) -------
__global__ __launch_bounds__(64) void gate_topk(
    const float* __restrict__ x, const float* __restrict__ gw,
    int* __restrict__ counts, int* __restrict__ tok_list,
    float* __restrict__ wt_list, int* __restrict__ slotA,
    int* __restrict__ slotB, unsigned short* __restrict__ xb)
{
  const int t = blockIdx.x;
  const int lane = threadIdx.x;
  const float* xr = x + (size_t)t * DDIM;
  unsigned short* xbr = xb + (size_t)t * DDIM;
  float p[NEXP];
#pragma unroll
  for (int e = 0; e < NEXP; ++e) p[e] = 0.f;
#pragma unroll 4
  for (int i = 0; i < DDIM / 64; ++i) {
    const int d = i * 64 + lane;
    const float xv = xr[d];
    xbr[d] = f2bf(xv);                       // fused convert_x (coalesced u16)
    const float4 g0 = *(const float4*)(gw + (size_t)d * NEXP);
    const float4 g1 = *(const float4*)(gw + (size_t)d * NEXP + 4);
    p[0] += xv * g0.x; p[1] += xv * g0.y; p[2] += xv * g0.z; p[3] += xv * g0.w;
    p[4] += xv * g1.x; p[5] += xv * g1.y; p[6] += xv * g1.z; p[7] += xv * g1.w;
  }
#pragma unroll
  for (int off = 32; off > 0; off >>= 1) {
#pragma unroll
    for (int e = 0; e < NEXP; ++e) p[e] += __shfl_down(p[e], off);
  }
  if (lane == 0) {
    int i1 = 0; float v1 = p[0];
#pragma unroll
    for (int e = 1; e < NEXP; ++e) if (p[e] > v1) { v1 = p[e]; i1 = e; }
    int i2 = -1; float v2 = -3.4e38f;
#pragma unroll
    for (int e = 0; e < NEXP; ++e) if (e != i1 && p[e] > v2) { v2 = p[e]; i2 = e; }
    const float w0 = 1.f / (1.f + __expf(v2 - v1));
    int q1 = atomicAdd(&counts[i1 * 32], 1);          // counters 128B apart
    tok_list[i1 * T_TOK + q1] = t;
    wt_list[i1 * T_TOK + q1] = w0;
    slotA[t] = i1 * T_TOK + q1;
    int q2 = atomicAdd(&counts[i2 * 32], 1);
    tok_list[i2 * T_TOK + q2] = t;
    wt_list[i2 * T_TOK + q2] = 1.f - w0;
    slotB[t] = i2 * T_TOK + q2;
  }
}

// ------------- prefix sum of counts + block dispatch tables ----------------
__global__ void calc_offs(const int* __restrict__ counts, int* __restrict__ offs,
                          int* __restrict__ t1e, int* __restrict__ t1p,
                          int* __restrict__ t2e, int* __restrict__ t2p)
{
  if (threadIdx.x == 0 && blockIdx.x == 0) {
    int a = 0;
#pragma unroll
    for (int e = 0; e < NEXP; ++e) { offs[e] = a; a += counts[e * 32]; }
    offs[NEXP] = a;
    int nb = 0;
    for (int e = 0; e < NEXP; ++e) {
      const int c = counts[e * 32];
      for (int p = 0; p < c; p += 256) { t1e[nb] = e; t1p[nb] = p; ++nb; }
    }
    offs[9] = nb;                     // gemm1 block count (<=72)
    nb = 0;
    for (int e = 0; e < NEXP; ++e) {
      const int c = counts[e * 32];
      for (int p = 0; p < c; p += 128) { t2e[nb] = e; t2p[nb] = p; ++nb; }
    }
    offs[10] = nb;                    // gemm2 block count (<=136)
  }
}

// ---------------- weight fp32 [K][N] tile -> bf16 [N][K], unit-swizzled ------
// stored 16B-unit U' at row n holds true k-unit (U'^(n&7)) so that a LINEAR
// global_load_lds of a [rows][64k] tile lands XOR-swizzled in LDS (m173/m201).
__device__ __forceinline__ void conv_tile(
    const float* __restrict__ se, unsigned short* __restrict__ de,
    int K, int N, int k0, int n0)
{
  __shared__ unsigned short Tb[64][130];     // +2 pad spreads phase-2 read banks
  const int tid = threadIdx.x;
#pragma unroll
  for (int i = 0; i < 8; ++i) {
    const int f = i * 256 + tid;             // 2048 float4 per 64x128 tile
    const int kl = f >> 5, nq = (f & 31) * 4;
    const float4 v = *(const float4*)(se + (size_t)(k0 + kl) * N + n0 + nq);
    Tb[kl][nq + 0] = f2bf(v.x);
    Tb[kl][nq + 1] = f2bf(v.y);
    Tb[kl][nq + 2] = f2bf(v.z);
    Tb[kl][nq + 3] = f2bf(v.w);
  }
  __syncthreads();
#pragma unroll
  for (int i = 0; i < 4; ++i) {
    const int idx = i * 256 + tid;           // 1024 output 16B units
    const int n = idx >> 3, up = idx & 7;
    const int kb = (up ^ (n & 7)) * 8;       // (n0+n)&7 == n&7 (n0 % 128 == 0)
    union { unsigned short s[8]; uint4 v; } t;
#pragma unroll
    for (int j = 0; j < 8; ++j) t.s[j] = Tb[kb + j][n];
    *(uint4*)(de + ((size_t)(n0 + n) * K + k0 + up * 8)) = t.v;
  }
}

// all three weights in one launch, flat tile enumeration (zero idle blocks)
__global__ __launch_bounds__(256) void convert_all(
    const float* __restrict__ w1, const float* __restrict__ w3,
    const float* __restrict__ w2, unsigned short* __restrict__ w1t,
    unsigned short* __restrict__ w3t, unsigned short* __restrict__ w2t)
{
  const int g = blockIdx.x;                  // 9216 tiles total
  const int seg = g / 3072, r = g % 3072;
  const int e = r / 384, rr = r % 384;
  if (seg < 2) {                             // w1/w3: K=DDIM(16 kb), N=HDIM(24 nb)
    const float* src = (seg == 0 ? w1 : w3) + (size_t)e * DDIM * HDIM;
    unsigned short* dst = (seg == 0 ? w1t : w3t) + (size_t)e * HDIM * DDIM;
    conv_tile(src, dst, DDIM, HDIM, (rr / 24) * 64, (rr % 24) * 128);
  } else {                                   // w2: K=HDIM(48 kb), N=DDIM(8 nb)
    conv_tile(w2 + (size_t)e * HDIM * DDIM, w2t + (size_t)e * DDIM * HDIM,
              HDIM, DDIM, (rr / 8) * 64, (rr % 8) * 128);
  }
}

// ---------------- GEMM1: h = silu(Xg@w1) * (Xg@w3), bf16 out ----------------
// 256 tok x 128 h-cols x BK=64, 8 waves (4M x 2N), per wave 64x64 per matrix.
// Counted-vmcnt prefetch double-buffer (T3/T4): stage t+1, wait OWN vmcnt(8),
// barrier, compute t. 128 KB LDS, 1 block/CU. T5 setprio around MFMA cluster.
__global__ __launch_bounds__(512, 2) void moe_gemm1(
    const unsigned short* __restrict__ xb, const unsigned short* __restrict__ w1t,
    const unsigned short* __restrict__ w3t, const int* __restrict__ counts,
    const int* __restrict__ offs, const int* __restrict__ t1e,
    const int* __restrict__ t1p, const int* __restrict__ tok_list,
    unsigned short* __restrict__ h_buf)
{
  const int b = blockIdx.y;
  if (b >= offs[9]) return;
  const int e = t1e[b];
  const int p0 = t1p[b];
  const int cnt = counts[e * 32];
  const int n0 = blockIdx.x * 128;
  const int hbase = offs[e];

  // 128 KB: A [2][256][64]@0, B1 [2][128][64]@32768, B3 @49152 (u16 indices)
  __shared__ __align__(16) unsigned short lds[65536];

  const int tid = threadIdx.x;
  const int lane = tid & 63;
  const int wv = tid >> 6;              // 0..7
  const int wm = wv >> 1;               // row-block 0..3 (64 rows each)
  const int wn = wv & 1;                // col-block 0..1 (64 cols each)
  const int lr = lane & 15;
  const int lg = lane >> 4;
  const int l8 = lane >> 3;
  const int lu = lane & 7;
  const int aswz = (lu ^ l8) * 16;      // pre-swizzled source for linear LDS dest

  const int* tl = tok_list + e * T_TOK;

  const char* asrc[4];
#pragma unroll
  for (int i = 0; i < 4; ++i) {
    const int p = p0 + wv * 32 + i * 8 + l8;
    const int tok = (p < cnt) ? tl[p] : 0;     // clamp: garbage rows never stored
    asrc[i] = (const char*)(xb + (size_t)tok * DDIM) + aswz;
  }
  const char* b1src[2];
  const char* b3src[2];
#pragma unroll
  for (int i = 0; i < 2; ++i) {
    const int n = n0 + wv * 16 + i * 8 + l8;   // n&7 == LDS row&7 (n0%128==0)
    b1src[i] = (const char*)(w1t + (size_t)(e * HDIM + n) * DDIM) + lu * 16;
    b3src[i] = (const char*)(w3t + (size_t)(e * HDIM + n) * DDIM) + lu * 16;
  }

  facc acc1[4][4], acc3[4][4];
#pragma unroll
  for (int m = 0; m < 4; ++m)
#pragma unroll
    for (int n = 0; n < 4; ++n)
#pragma unroll
      for (int q = 0; q < 4; ++q) { acc1[m][n][q] = 0.f; acc3[m][n][q] = 0.f; }

  // ---- stage K-tile t into buffer s: 8 gload16 per thread ----
#define STAGE1(k0, s)                                                          \
  {                                                                            \
    const int koff = (k0) * 2;                                                 \
    unsigned short* A = lds + (s) * 16384;                                     \
    unsigned short* B1 = lds + 32768 + (s) * 8192;                             \
    unsigned short* B3 = lds + 49152 + (s) * 8192;                             \
    _Pragma("unroll") for (int i = 0; i < 4; ++i)                              \
        gload16(asrc[i] + koff, &A[(wv * 4 + i) * 512]);                       \
    _Pragma("unroll") for (int i = 0; i < 2; ++i) {                            \
      gload16(b1src[i] + koff, &B1[(wv * 2 + i) * 512]);                       \
      gload16(b3src[i] + koff, &B3[(wv * 2 + i) * 512]);                       \
    }                                                                          \
  }

  STAGE1(0, 0);
#pragma unroll 1
  for (int t = 0; t < 16; ++t) {
    const int s = t & 1;
    if (t < 15) {
      STAGE1((t + 1) * 64, s ^ 1);
      asm volatile("s_waitcnt vmcnt(8)" ::: "memory");   // own tile-t loads done
    } else {
      asm volatile("s_waitcnt vmcnt(0)" ::: "memory");
    }
    __builtin_amdgcn_s_barrier();                        // everyone's landed
    asm volatile("" ::: "memory");
    const unsigned short* A = lds + s * 16384;
    const unsigned short* B1 = lds + 32768 + s * 8192;
    const unsigned short* B3 = lds + 49152 + s * 8192;
    __builtin_amdgcn_s_setprio(1);
#pragma unroll
    for (int ks = 0; ks < 2; ++ks) {
      bfrag a[4];
#pragma unroll
      for (int m = 0; m < 4; ++m) {
        const int rr = wm * 64 + m * 16 + lr;
        const int u = (ks * 4 + lg) ^ (rr & 7);
        a[m] = *(const bfrag*)&A[rr * 64 + u * 8];
      }
#pragma unroll
      for (int n = 0; n < 4; ++n) {
        const int rb = wn * 64 + n * 16 + lr;
        const int u = (ks * 4 + lg) ^ (rb & 7);
        const bfrag b1 = *(const bfrag*)&B1[rb * 64 + u * 8];
#pragma unroll
        for (int m = 0; m < 4; ++m)
          acc1[m][n] = __builtin_amdgcn_mfma_f32_16x16x32_bf16(a[m], b1, acc1[m][n], 0, 0, 0);
        const bfrag b3 = *(const bfrag*)&B3[rb * 64 + u * 8];
#pragma unroll
        for (int m = 0; m < 4; ++m)
          acc3[m][n] = __builtin_amdgcn_mfma_f32_16x16x32_bf16(a[m], b3, acc3[m][n], 0, 0, 0);
      }
    }
    __builtin_amdgcn_s_setprio(0);
    asm volatile("" ::: "memory");
    __builtin_amdgcn_s_barrier();                        // done reading buf s
  }
#undef STAGE1

  // epilogue: h = silu(a1)*a3 -> lds as plain [256][128] -> coalesced store
#pragma unroll
  for (int m = 0; m < 4; ++m)
#pragma unroll
    for (int n = 0; n < 4; ++n)
#pragma unroll
      for (int q = 0; q < 4; ++q) {
        const float a1 = acc1[m][n][q];
        const float a3 = acc3[m][n][q];
        const float hv = a1 * a3 / (1.f + __expf(-a1));
        const int row = wm * 64 + m * 16 + lg * 4 + q;
        const int col = wn * 64 + n * 16 + lr;
        lds[row * 128 + col] = f2bf(hv);
      }
  __syncthreads();
#pragma unroll
  for (int i = 0; i < 8; ++i) {
    const int idx = i * 512 + tid;        // 4096 16B units in 256x128 tile
    const int r = idx >> 4, u = idx & 15;
    if (p0 + r < cnt)
      *(uint4*)(h_buf + ((size_t)(hbase + p0 + r) * HDIM + n0 + u * 8)) =
          *(const uint4*)&lds[r * 128 + u * 8];
  }
}

// ---------------- GEMM2: part[pos] = h @ w2 (no atomics) ----------------
// table-dispatched. tile 128 pos x 128 d-cols x BK=64, per wave 64x64.
__global__ __launch_bounds__(256, 2) void moe_gemm2(
    const unsigned short* __restrict__ h_buf, const unsigned short* __restrict__ w2t,
    const int* __restrict__ counts, const int* __restrict__ offs,
    const int* __restrict__ t2e, const int* __restrict__ t2p,
    float* __restrict__ part)
{
  const int b = blockIdx.y;
  if (b >= offs[10]) return;
  const int e = t2e[b];
  const int p0 = t2p[b];
  const int cnt = counts[e * 32];
  const int n0 = blockIdx.x * 128;
  const int hbase = offs[e];

  __shared__ __align__(16) unsigned short Ah[128 * 64];
  __shared__ __align__(16) unsigned short Bw[128 * 64];

  const int tid = threadIdx.x;
  const int lane = tid & 63;
  const int wv = tid >> 6;
  const int wm = wv >> 1;
  const int wn = wv & 1;
  const int lr = lane & 15;
  const int lg = lane >> 4;
  const int l8 = lane >> 3;
  const int lu = lane & 7;
  const int aswz = (lu ^ l8) * 16;

  const unsigned short* asrc[4];
#pragma unroll
  for (int i = 0; i < 4; ++i) {
    const int p = p0 + wv * 32 + i * 8 + l8;
    const int hrow = hbase + ((p < cnt) ? p : 0);  // clamp to valid written row
    asrc[i] = h_buf + (size_t)hrow * HDIM;
  }
  const unsigned short* bsrc[4];
#pragma unroll
  for (int i = 0; i < 4; ++i) {
    const int n = n0 + wv * 32 + i * 8 + l8;
    bsrc[i] = w2t + (size_t)(e * DDIM + n) * HDIM;   // swizzle baked in storage
  }

  facc acc[4][4];
#pragma unroll
  for (int m = 0; m < 4; ++m)
#pragma unroll
    for (int n = 0; n < 4; ++n)
#pragma unroll
      for (int q = 0; q < 4; ++q) acc[m][n][q] = 0.f;

#pragma unroll 1
  for (int k0 = 0; k0 < HDIM; k0 += 64) {
#pragma unroll
    for (int i = 0; i < 4; ++i)
      gload16((const char*)asrc[i] + k0 * 2 + aswz, &Ah[(wv * 4 + i) * 512]);
#pragma unroll
    for (int i = 0; i < 4; ++i)
      gload16((const char*)bsrc[i] + k0 * 2 + lu * 16, &Bw[(wv * 4 + i) * 512]);
    __syncthreads();
#pragma unroll
    for (int ks = 0; ks < 2; ++ks) {
      bfrag a[4];
#pragma unroll
      for (int m = 0; m < 4; ++m) {
        const int r = wm * 64 + m * 16 + lr;
        const int u = (ks * 4 + lg) ^ (r & 7);
        a[m] = *(const bfrag*)&Ah[r * 64 + u * 8];
      }
#pragma unroll
      for (int n = 0; n < 4; ++n) {
        const int rb = wn * 64 + n * 16 + lr;
        const int u = (ks * 4 + lg) ^ (rb & 7);
        const bfrag bb = *(const bfrag*)&Bw[rb * 64 + u * 8];
#pragma unroll
        for (int m = 0; m < 4; ++m)
          acc[m][n] = __builtin_amdgcn_mfma_f32_16x16x32_bf16(a[m], bb, acc[m][n], 0, 0, 0);
      }
    }
    __syncthreads();
  }

#pragma unroll
  for (int m = 0; m < 4; ++m)
#pragma unroll
    for (int q = 0; q < 4; ++q) {
      const int p = p0 + wm * 64 + m * 16 + lg * 4 + q;
      if (p < cnt) {
        float* dst = part + (size_t)(hbase + p) * DDIM + n0 + wn * 64 + lr;
#pragma unroll
        for (int n = 0; n < 4; ++n)
          dst[n * 16] = acc[m][n][q];
      }
    }
}

// ---------------- combine: out[t] = wA*part[posA] + wB*part[posB] ----------------
__global__ __launch_bounds__(256) void combine_out(
    const float* __restrict__ part, const int* __restrict__ slotA,
    const int* __restrict__ slotB, const float* __restrict__ wt_list,
    const int* __restrict__ offs, float* __restrict__ out)
{
  const int t = blockIdx.x;
  const int sA = slotA[t], sB = slotB[t];
  const float wA = wt_list[sA], wB = wt_list[sB];
  const int pA = offs[sA >> 13] + (sA & (T_TOK - 1));
  const int pB = offs[sB >> 13] + (sB & (T_TOK - 1));
  const float* ra = part + (size_t)pA * DDIM;
  const float* rb = part + (size_t)pB * DDIM;
  float* o = out + (size_t)t * DDIM;
  const int i = threadIdx.x * 4;
  const float4 a = *(const float4*)(ra + i);
  const float4 b = *(const float4*)(rb + i);
  float4 r;
  r.x = wA * a.x + wB * b.x;
  r.y = wA * a.y + wB * b.y;
  r.z = wA * a.z + wB * b.z;
  r.w = wA * a.w + wB * b.w;
  *(float4*)(o + i) = r;
}

// ================= fallback path (previous verified kernels) =================
__global__ __launch_bounds__(64) void gate_topk_fb(
    const float* __restrict__ x, const float* __restrict__ gw,
    int* __restrict__ counts, int* __restrict__ tok_list,
    float* __restrict__ wt_list)
{
  const int t = blockIdx.x;
  const int lane = threadIdx.x;
  const float* xr = x + (size_t)t * DDIM;
  float p[NEXP];
#pragma unroll
  for (int e = 0; e < NEXP; ++e) p[e] = 0.f;
#pragma unroll 4
  for (int i = 0; i < DDIM / 64; ++i) {
    const int d = i * 64 + lane;
    const float xv = xr[d];
    const float4 g0 = *(const float4*)(gw + (size_t)d * NEXP);
    const float4 g1 = *(const float4*)(gw + (size_t)d * NEXP + 4);
    p[0] += xv * g0.x; p[1] += xv * g0.y; p[2] += xv * g0.z; p[3] += xv * g0.w;
    p[4] += xv * g1.x; p[5] += xv * g1.y; p[6] += xv * g1.z; p[7] += xv * g1.w;
  }
#pragma unroll
  for (int off = 32; off > 0; off >>= 1) {
#pragma unroll
    for (int e = 0; e < NEXP; ++e) p[e] += __shfl_down(p[e], off);
  }
  if (lane == 0) {
    int i1 = 0; float v1 = p[0];
#pragma unroll
    for (int e = 1; e < NEXP; ++e) if (p[e] > v1) { v1 = p[e]; i1 = e; }
    int i2 = -1; float v2 = -3.4e38f;
#pragma unroll
    for (int e = 0; e < NEXP; ++e) if (e != i1 && p[e] > v2) { v2 = p[e]; i2 = e; }
    const float w0 = 1.f / (1.f + __expf(v2 - v1));
    int q1 = atomicAdd(&counts[i1 * 32], 1);
    tok_list[i1 * T_TOK + q1] = t;
    wt_list[i1 * T_TOK + q1] = w0;
    int q2 = atomicAdd(&counts[i2 * 32], 1);
    tok_list[i2 * T_TOK + q2] = t;
    wt_list[i2 * T_TOK + q2] = 1.f - w0;
  }
}

__global__ __launch_bounds__(256) void moe_gemm1_fb(
    const float* __restrict__ x, const float* __restrict__ w1,
    const float* __restrict__ w3, const int* __restrict__ counts,
    const int* __restrict__ tok_list, unsigned short* __restrict__ h_buf,
    int e)
{
  const int cnt = counts[e * 32];
  const int p0 = blockIdx.y * 64;
  if (p0 >= cnt) return;
  const int n0 = blockIdx.x * 64;

  __shared__ unsigned short As[64][40];
  __shared__ unsigned short B1s[64][40];
  __shared__ unsigned short B3s[64][40];

  const int tid = threadIdx.x;
  const int lane = tid & 63;
  const int wv = tid >> 6;

  const float* w1e = w1 + (size_t)e * DDIM * HDIM;
  const float* w3e = w3 + (size_t)e * DDIM * HDIM;
  const int* tl = tok_list + e * T_TOK;

  const int arow = tid >> 2;
  const int akseg = (tid & 3) * 8;
  int tok = -1;
  if (p0 + arow < cnt) tok = tl[p0 + arow];

  const int bk = tid >> 3;
  const int bn4 = (tid & 7) * 4;

  facc acc1[4], acc3[4];
#pragma unroll
  for (int i = 0; i < 4; ++i)
#pragma unroll
    for (int j = 0; j < 4; ++j) { acc1[i][j] = 0.f; acc3[i][j] = 0.f; }

  const int mrow = wv * 16 + (lane & 15);
  const int kq = (lane >> 4) * 8;

  for (int k0 = 0; k0 < DDIM; k0 += 32) {
    {
      union { unsigned short s[8]; uint4 v; } tmp;
      if (tok >= 0) {
        const float* src = x + (size_t)tok * DDIM + k0 + akseg;
        const float4 f0 = *(const float4*)(src);
        const float4 f1 = *(const float4*)(src + 4);
        tmp.s[0]=f2bf(f0.x); tmp.s[1]=f2bf(f0.y); tmp.s[2]=f2bf(f0.z); tmp.s[3]=f2bf(f0.w);
        tmp.s[4]=f2bf(f1.x); tmp.s[5]=f2bf(f1.y); tmp.s[6]=f2bf(f1.z); tmp.s[7]=f2bf(f1.w);
      } else {
        tmp.v = make_uint4(0u, 0u, 0u, 0u);
      }
      *(uint4*)&As[arow][akseg] = tmp.v;
    }
#pragma unroll
    for (int pass = 0; pass < 2; ++pass) {
      const int n = bn4 + pass * 32;
      const float4 f1v = *(const float4*)(w1e + (size_t)(k0 + bk) * HDIM + n0 + n);
      B1s[n + 0][bk] = f2bf(f1v.x);
      B1s[n + 1][bk] = f2bf(f1v.y);
      B1s[n + 2][bk] = f2bf(f1v.z);
      B1s[n + 3][bk] = f2bf(f1v.w);
      const float4 f3v = *(const float4*)(w3e + (size_t)(k0 + bk) * HDIM + n0 + n);
      B3s[n + 0][bk] = f2bf(f3v.x);
      B3s[n + 1][bk] = f2bf(f3v.y);
      B3s[n + 2][bk] = f2bf(f3v.z);
      B3s[n + 3][bk] = f2bf(f3v.w);
    }
    __syncthreads();
    const bfrag a = *(const bfrag*)&As[mrow][kq];
#pragma unroll
    for (int nt = 0; nt < 4; ++nt) {
      const bfrag b1 = *(const bfrag*)&B1s[nt * 16 + (lane & 15)][kq];
      acc1[nt] = __builtin_amdgcn_mfma_f32_16x16x32_bf16(a, b1, acc1[nt], 0, 0, 0);
      const bfrag b3 = *(const bfrag*)&B3s[nt * 16 + (lane & 15)][kq];
      acc3[nt] = __builtin_amdgcn_mfma_f32_16x16x32_bf16(a, b3, acc3[nt], 0, 0, 0);
    }
    __syncthreads();
  }
  const int rbase = p0 + wv * 16 + ((lane >> 4) * 4);
  const int cbase = n0 + (lane & 15);
#pragma unroll
  for (int r = 0; r < 4; ++r) {
    const int p = rbase + r;
    if (p < cnt) {
      unsigned short* dst = h_buf + (size_t)p * HDIM + cbase;
#pragma unroll
      for (int nt = 0; nt < 4; ++nt) {
        const float a1 = acc1[nt][r];
        const float a3 = acc3[nt][r];
        const float hv = a1 * a3 / (1.f + __expf(-a1));
        dst[nt * 16] = f2bf(hv);
      }
    }
  }
}

__global__ __launch_bounds__(256) void moe_gemm2_fb(
    const unsigned short* __restrict__ h_buf, const float* __restrict__ w2,
    const int* __restrict__ counts, const int* __restrict__ tok_list,
    const float* __restrict__ wt_list, float* __restrict__ out, int e)
{
  const int cnt = counts[e * 32];
  const int p0 = blockIdx.y * 64;
  if (p0 >= cnt) return;
  const int n0 = blockIdx.x * 64;

  __shared__ unsigned short As[64][40];
  __shared__ unsigned short Bs[64][40];

  const int tid = threadIdx.x;
  const int lane = tid & 63;
  const int wv = tid >> 6;

  const float* w2e = w2 + (size_t)e * HDIM * DDIM;
  const int* tl = tok_list + e * T_TOK;
  const float* wl = wt_list + e * T_TOK;

  const int arow = tid >> 2;
  const int akseg = (tid & 3) * 8;
  const bool avalid = (p0 + arow < cnt);

  const int bk = tid >> 3;
  const int bn4 = (tid & 7) * 4;

  facc acc[4];
#pragma unroll
  for (int i = 0; i < 4; ++i)
#pragma unroll
    for (int j = 0; j < 4; ++j) acc[i][j] = 0.f;

  const int mrow = wv * 16 + (lane & 15);
  const int kq = (lane >> 4) * 8;

  for (int k0 = 0; k0 < HDIM; k0 += 32) {
    if (avalid) {
      *(uint4*)&As[arow][akseg] =
          *(const uint4*)(h_buf + (size_t)(p0 + arow) * HDIM + k0 + akseg);
    } else {
      *(uint4*)&As[arow][akseg] = make_uint4(0u, 0u, 0u, 0u);
    }
#pragma unroll
    for (int pass = 0; pass < 2; ++pass) {
      const int n = bn4 + pass * 32;
      const float4 f = *(const float4*)(w2e + (size_t)(k0 + bk) * DDIM + n0 + n);
      Bs[n + 0][bk] = f2bf(f.x);
      Bs[n + 1][bk] = f2bf(f.y);
      Bs[n + 2][bk] = f2bf(f.z);
      Bs[n + 3][bk] = f2bf(f.w);
    }
    __syncthreads();
    const bfrag a = *(const bfrag*)&As[mrow][kq];
#pragma unroll
    for (int nt = 0; nt < 4; ++nt) {
      const bfrag b = *(const bfrag*)&Bs[nt * 16 + (lane & 15)][kq];
      acc[nt] = __builtin_amdgcn_mfma_f32_16x16x32_bf16(a, b, acc[nt], 0, 0, 0);
    }
    __syncthreads();
  }
  const int rbase = p0 + wv * 16 + ((lane >> 4) * 4);
  const int cbase = n0 + (lane & 15);
#pragma unroll
  for (int r = 0; r < 4; ++r) {
    const int p = rbase + r;
    if (p < cnt) {
      const int tok = tl[p];
      const float wt = wl[p];
      float* dst = out + (size_t)tok * DDIM + cbase;
#pragma unroll
      for (int nt = 0; nt < 4; ++nt) {
        atomicAdd(dst + nt * 16, acc[nt][r] * wt);
      }
    }
  }
}

__global__ void ws_too_small(float* out, int n) {
  int i = blockIdx.x * 256 + threadIdx.x;
  if (i < n) out[i] = 1.0e6f;   // sentinel: workspace shortage, not a math bug
}

extern "C" void kernel_launch(void* const* d_in, const int* in_sizes, int n_in,
                              void* d_out, int out_size, void* d_ws, size_t ws_size,
                              hipStream_t stream) {
  // setup_inputs dict order: x, gate_w, w1, w3, w2
  const float* x  = (const float*)d_in[0];
  const float* gw = (const float*)d_in[1];
  const float* w1 = (const float*)d_in[2];
  const float* w3 = (const float*)d_in[3];
  const float* w2 = (const float*)d_in[4];
  float* out = (float*)d_out;

  // ---- new-path workspace layout (bf16 weights pre-transposed+swizzled) ----
  // [0,1024): counts (8 ints, 128B apart); [1024,2048): offs (incl. blk counts)
  // [2048,4096): dispatch tables t1e[80] t1p[80] t2e[136] t2p[136]
  const size_t off_tok = 4096;
  const size_t off_wt  = off_tok + (size_t)NEXP * T_TOK * 4;
  const size_t off_sA  = off_wt + (size_t)NEXP * T_TOK * 4;      // slotA [T_TOK]
  const size_t off_sB  = off_sA + (size_t)T_TOK * 4;             // slotB [T_TOK]
  const size_t off_xb  = off_sB + (size_t)T_TOK * 4;
  const size_t off_w1t = off_xb + (size_t)T_TOK * DDIM * 2;
  const size_t off_w3t = off_w1t + (size_t)NEXP * DDIM * HDIM * 2;
  const size_t off_w2t = off_w3t + (size_t)NEXP * DDIM * HDIM * 2;
  const size_t off_h   = off_w2t + (size_t)NEXP * HDIM * DDIM * 2;
  const size_t need    = off_h + (size_t)(2 * T_TOK) * HDIM * 2; // sum(cnt)=2*T_TOK
  // part[2*T_TOK][DDIM] fp32 (64 MB) ALIASES w1t+w3t (100 MB, dead after gemm1)
  const size_t off_part = off_w1t;

  if (ws_size >= need) {
    int* counts = (int*)d_ws;
    int* offs = (int*)((char*)d_ws + 1024);
    int* t1e = (int*)((char*)d_ws + 2048);
    int* t1p = (int*)((char*)d_ws + 2368);
    int* t2e = (int*)((char*)d_ws + 2688);
    int* t2p = (int*)((char*)d_ws + 3232);
    int* tok_list = (int*)((char*)d_ws + off_tok);
    float* wt_list = (float*)((char*)d_ws + off_wt);
    int* slotA = (int*)((char*)d_ws + off_sA);
    int* slotB = (int*)((char*)d_ws + off_sB);
    unsigned short* xb  = (unsigned short*)((char*)d_ws + off_xb);
    unsigned short* w1t = (unsigned short*)((char*)d_ws + off_w1t);
    unsigned short* w3t = (unsigned short*)((char*)d_ws + off_w3t);
    unsigned short* w2t = (unsigned short*)((char*)d_ws + off_w2t);
    unsigned short* h_buf = (unsigned short*)((char*)d_ws + off_h);
    float* part = (float*)((char*)d_ws + off_part);

    hipMemsetAsync(d_ws, 0, 4096, stream);

    convert_all<<<9216, 256, 0, stream>>>(w1, w3, w2, w1t, w3t, w2t);
    gate_topk<<<T_TOK, 64, 0, stream>>>(x, gw, counts, tok_list, wt_list,
                                        slotA, slotB, xb);
    calc_offs<<<1, 1, 0, stream>>>(counts, offs, t1e, t1p, t2e, t2p);
    moe_gemm1<<<dim3(HDIM / 128, 72), 512, 0, stream>>>(
        xb, w1t, w3t, counts, offs, t1e, t1p, tok_list, h_buf);
    moe_gemm2<<<dim3(DDIM / 128, 136), 256, 0, stream>>>(
        h_buf, w2t, counts, offs, t2e, t2p, part);
    combine_out<<<T_TOK, 256, 0, stream>>>(part, slotA, slotB, wt_list, offs, out);
    return;
  }

  // ---- fallback: previous verified path (fp32 weights, per-expert loop) ----
  const size_t fb_off_tok = 1024;
  const size_t fb_off_wt  = fb_off_tok + (size_t)NEXP * T_TOK * 4;
  const size_t fb_off_h   = fb_off_wt + (size_t)NEXP * T_TOK * 4;
  const size_t fb_need    = fb_off_h + (size_t)T_TOK * HDIM * 2;
  if (ws_size < fb_need) {
    ws_too_small<<<(out_size + 255) / 256, 256, 0, stream>>>(out, out_size);
    return;
  }
  int* counts = (int*)d_ws;
  int* tok_list = (int*)((char*)d_ws + fb_off_tok);
  float* wt_list = (float*)((char*)d_ws + fb_off_wt);
  unsigned short* h_buf = (unsigned short*)((char*)d_ws + fb_off_h);

  hipMemsetAsync(counts, 0, 1024, stream);
  hipMemsetAsync(out, 0, (size_t)out_size * sizeof(float), stream);

  gate_topk_fb<<<T_TOK, 64, 0, stream>>>(x, gw, counts, tok_list, wt_list);
  for (int e = 0; e < NEXP; ++e) {
    moe_gemm1_fb<<<dim3(HDIM / 64, T_TOK / 64), 256, 0, stream>>>(
        x, w1, w3, counts, tok_list, h_buf, e);
    moe_gemm2_fb<<<dim3(DDIM / 64, T_TOK / 64), 256, 0, stream>>>(
        h_buf, w2, counts, tok_list, wt_list, out, e);
  }
}

// Round 6
// 718.141 us; speedup vs baseline: 1.0456x; 1.0456x over previous
//
#include <hip/hip_runtime.h>
#include <stdint.h>

#define T_TOK 8192
#define DDIM 1024
#define NEXP 8
#define HDIM 3072

typedef __attribute__((ext_vector_type(8))) short bfrag;   // 8 bf16 in 4 VGPRs
typedef __attribute__((ext_vector_type(4))) float facc;    // 4 fp32 acc

// async global->LDS, 16B per lane; LDS dest must be wave-uniform base (+lane*16)
__device__ __forceinline__ void gload16(const void* g, void* l) {
  __builtin_amdgcn_global_load_lds(
      (const __attribute__((address_space(1))) void*)g,
      (__attribute__((address_space(3))) void*)l, 16, 0, 0);
}

__device__ __forceinline__ unsigned short f2bf(float f) {
  unsigned int u = __float_as_uint(f);
  u += 0x7FFFu + ((u >> 16) & 1u);      // round-to-nearest-even
  return (unsigned short)(u >> 16);
}

// ------------- prefix sum of counts + block dispatch tables ----------------
__global__ void calc_offs(const int* __restrict__ counts, int* __restrict__ offs,
                          int* __restrict__ t1e, int* __restrict__ t1p,
                          int* __restrict__ t2e, int* __restrict__ t2p)
{
  if (threadIdx.x == 0 && blockIdx.x == 0) {
    int a = 0;
#pragma unroll
    for (int e = 0; e < NEXP; ++e) { offs[e] = a; a += counts[e * 32]; }
    offs[NEXP] = a;
    int nb = 0;
    for (int e = 0; e < NEXP; ++e) {
      const int c = counts[e * 32];
      for (int p = 0; p < c; p += 128) { t1e[nb] = e; t1p[nb] = p; ++nb; }
    }
    offs[9] = nb;                     // gemm1 block count (<=135)
    nb = 0;
    for (int e = 0; e < NEXP; ++e) {
      const int c = counts[e * 32];
      for (int p = 0; p < c; p += 128) { t2e[nb] = e; t2p[nb] = p; ++nb; }
    }
    offs[10] = nb;                    // gemm2 block count (<=135)
  }
}

// ---------------- weight fp32 [K][N] tile -> bf16 [N][K], unit-swizzled ------
// stored 16B-unit U' at row n holds true k-unit (U'^(n&7)) so that a LINEAR
// global_load_lds of a [rows][64k] tile lands XOR-swizzled in LDS (m173/m201).
__device__ __forceinline__ void conv_tile(
    const float* __restrict__ se, unsigned short* __restrict__ de,
    int K, int N, int k0, int n0)
{
  __shared__ unsigned short Tb[64][130];     // +2 pad spreads phase-2 read banks
  const int tid = threadIdx.x;
#pragma unroll
  for (int i = 0; i < 8; ++i) {
    const int f = i * 256 + tid;             // 2048 float4 per 64x128 tile
    const int kl = f >> 5, nq = (f & 31) * 4;
    const float4 v = *(const float4*)(se + (size_t)(k0 + kl) * N + n0 + nq);
    Tb[kl][nq + 0] = f2bf(v.x);
    Tb[kl][nq + 1] = f2bf(v.y);
    Tb[kl][nq + 2] = f2bf(v.z);
    Tb[kl][nq + 3] = f2bf(v.w);
  }
  __syncthreads();
#pragma unroll
  for (int i = 0; i < 4; ++i) {
    const int idx = i * 256 + tid;           // 1024 output 16B units
    const int n = idx >> 3, up = idx & 7;
    const int kb = (up ^ (n & 7)) * 8;       // (n0+n)&7 == n&7 (n0 % 128 == 0)
    union { unsigned short s[8]; uint4 v; } t;
#pragma unroll
    for (int j = 0; j < 8; ++j) t.s[j] = Tb[kb + j][n];
    *(uint4*)(de + ((size_t)(n0 + n) * K + k0 + up * 8)) = t.v;
  }
}

// ---- mega-kernel: weight converts (blocks 0..9215) + gating (9216..11263) ----
// gate: 4 waves/block, one token per wave, fused x->bf16 convert.
__global__ __launch_bounds__(256) void convert_gate(
    const float* __restrict__ w1, const float* __restrict__ w3,
    const float* __restrict__ w2, unsigned short* __restrict__ w1t,
    unsigned short* __restrict__ w3t, unsigned short* __restrict__ w2t,
    const float* __restrict__ x, const float* __restrict__ gw,
    int* __restrict__ counts, int* __restrict__ tok_list,
    float* __restrict__ wt_list, int* __restrict__ slotA,
    int* __restrict__ slotB, unsigned short* __restrict__ xb)
{
  const int g = blockIdx.x;
  if (g < 9216) {                            // weight tiles
    const int seg = g / 3072, r = g % 3072;
    const int e = r / 384, rr = r % 384;
    if (seg < 2) {                           // w1/w3: K=DDIM(16 kb), N=HDIM(24 nb)
      const float* src = (seg == 0 ? w1 : w3) + (size_t)e * DDIM * HDIM;
      unsigned short* dst = (seg == 0 ? w1t : w3t) + (size_t)e * HDIM * DDIM;
      conv_tile(src, dst, DDIM, HDIM, (rr / 24) * 64, (rr % 24) * 128);
    } else {                                 // w2: K=HDIM(48 kb), N=DDIM(8 nb)
      conv_tile(w2 + (size_t)e * HDIM * DDIM, w2t + (size_t)e * DDIM * HDIM,
                HDIM, DDIM, (rr / 8) * 64, (rr % 8) * 128);
    }
    return;
  }
  // ---- gating: token t, one wave ----
  const int lane = threadIdx.x & 63;
  const int t = (g - 9216) * 4 + (threadIdx.x >> 6);
  const float* xr = x + (size_t)t * DDIM;
  unsigned short* xbr = xb + (size_t)t * DDIM;
  float p[NEXP];
#pragma unroll
  for (int e = 0; e < NEXP; ++e) p[e] = 0.f;
#pragma unroll 4
  for (int i = 0; i < DDIM / 64; ++i) {
    const int d = i * 64 + lane;
    const float xv = xr[d];
    xbr[d] = f2bf(xv);                       // fused convert_x (coalesced u16)
    const float4 g0 = *(const float4*)(gw + (size_t)d * NEXP);
    const float4 g1 = *(const float4*)(gw + (size_t)d * NEXP + 4);
    p[0] += xv * g0.x; p[1] += xv * g0.y; p[2] += xv * g0.z; p[3] += xv * g0.w;
    p[4] += xv * g1.x; p[5] += xv * g1.y; p[6] += xv * g1.z; p[7] += xv * g1.w;
  }
#pragma unroll
  for (int off = 32; off > 0; off >>= 1) {
#pragma unroll
    for (int e = 0; e < NEXP; ++e) p[e] += __shfl_down(p[e], off);
  }
  if (lane == 0) {
    int i1 = 0; float v1 = p[0];
#pragma unroll
    for (int e = 1; e < NEXP; ++e) if (p[e] > v1) { v1 = p[e]; i1 = e; }
    int i2 = -1; float v2 = -3.4e38f;
#pragma unroll
    for (int e = 0; e < NEXP; ++e) if (e != i1 && p[e] > v2) { v2 = p[e]; i2 = e; }
    const float w0 = 1.f / (1.f + __expf(v2 - v1));
    int q1 = atomicAdd(&counts[i1 * 32], 1);          // counters 128B apart
    tok_list[i1 * T_TOK + q1] = t;
    wt_list[i1 * T_TOK + q1] = w0;
    slotA[t] = i1 * T_TOK + q1;
    int q2 = atomicAdd(&counts[i2 * 32], 1);
    tok_list[i2 * T_TOK + q2] = t;
    wt_list[i2 * T_TOK + q2] = 1.f - w0;
    slotB[t] = i2 * T_TOK + q2;
  }
}

// ---------------- GEMM1: h = silu(Xg@w1) * (Xg@w3), bf16 out ----------------
// VERIFIED shape: tile 128 tok x 64 h-cols x BK=64, 4 waves (2M x 2N),
// per wave 64x32 per output mat. 32 KB LDS, ~3.4 blocks/CU, 224 us measured.
// Table-dispatched (zero empty blocks).
__global__ __launch_bounds__(256, 2) void moe_gemm1(
    const unsigned short* __restrict__ xb, const unsigned short* __restrict__ w1t,
    const unsigned short* __restrict__ w3t, const int* __restrict__ counts,
    const int* __restrict__ offs, const int* __restrict__ t1e,
    const int* __restrict__ t1p, const int* __restrict__ tok_list,
    unsigned short* __restrict__ h_buf)
{
  const int b = blockIdx.y;
  if (b >= offs[9]) return;
  const int e = t1e[b];
  const int p0 = t1p[b];
  const int cnt = counts[e * 32];
  const int n0 = blockIdx.x * 64;
  const int hbase = offs[e];

  __shared__ __align__(16) unsigned short As[128 * 64];   // 16 KB, [row][64k] swz
  __shared__ __align__(16) unsigned short B1s[64 * 64];   // 8 KB, [n][64k] swz
  __shared__ __align__(16) unsigned short B3s[64 * 64];

  const int tid = threadIdx.x;
  const int lane = tid & 63;
  const int wv = tid >> 6;
  const int wm = wv >> 1;               // wave row-block (0..1) -> 64 rows
  const int wn = wv & 1;                // wave col-block (0..1) -> 32 cols
  const int lr = lane & 15;
  const int lg = lane >> 4;
  const int l8 = lane >> 3;             // staged row within 8-row chunk
  const int lu = lane & 7;              // staged 16B unit within row
  const int aswz = (lu ^ l8) * 16;      // per-lane source XOR for A (x is linear)

  const int* tl = tok_list + e * T_TOK;

  const unsigned short* asrc[4];
#pragma unroll
  for (int i = 0; i < 4; ++i) {
    const int p = p0 + wv * 32 + i * 8 + l8;
    const int tok = (p < cnt) ? tl[p] : 0;   // clamp: garbage rows never stored
    asrc[i] = xb + (size_t)tok * DDIM;
  }
  const unsigned short* b1src[2];
  const unsigned short* b3src[2];
#pragma unroll
  for (int i = 0; i < 2; ++i) {
    const int n = n0 + wv * 16 + i * 8 + l8;
    b1src[i] = w1t + (size_t)(e * HDIM + n) * DDIM;   // swizzle baked in storage
    b3src[i] = w3t + (size_t)(e * HDIM + n) * DDIM;
  }

  facc acc1[4][2], acc3[4][2];
#pragma unroll
  for (int m = 0; m < 4; ++m)
#pragma unroll
    for (int n = 0; n < 2; ++n)
#pragma unroll
      for (int q = 0; q < 4; ++q) { acc1[m][n][q] = 0.f; acc3[m][n][q] = 0.f; }

#pragma unroll 1
  for (int k0 = 0; k0 < DDIM; k0 += 64) {
#pragma unroll
    for (int i = 0; i < 4; ++i)
      gload16((const char*)asrc[i] + k0 * 2 + aswz, &As[(wv * 4 + i) * 512]);
#pragma unroll
    for (int i = 0; i < 2; ++i) {
      gload16((const char*)b1src[i] + k0 * 2 + lu * 16, &B1s[(wv * 2 + i) * 512]);
      gload16((const char*)b3src[i] + k0 * 2 + lu * 16, &B3s[(wv * 2 + i) * 512]);
    }
    __syncthreads();
#pragma unroll
    for (int ks = 0; ks < 2; ++ks) {
      bfrag a[4];
#pragma unroll
      for (int m = 0; m < 4; ++m) {
        const int r = wm * 64 + m * 16 + lr;
        const int u = (ks * 4 + lg) ^ (r & 7);
        a[m] = *(const bfrag*)&As[r * 64 + u * 8];
      }
#pragma unroll
      for (int n = 0; n < 2; ++n) {
        const int rb = wn * 32 + n * 16 + lr;
        const int u = (ks * 4 + lg) ^ (rb & 7);
        const bfrag b1 = *(const bfrag*)&B1s[rb * 64 + u * 8];
#pragma unroll
        for (int m = 0; m < 4; ++m)
          acc1[m][n] = __builtin_amdgcn_mfma_f32_16x16x32_bf16(a[m], b1, acc1[m][n], 0, 0, 0);
        const bfrag b3 = *(const bfrag*)&B3s[rb * 64 + u * 8];
#pragma unroll
        for (int m = 0; m < 4; ++m)
          acc3[m][n] = __builtin_amdgcn_mfma_f32_16x16x32_bf16(a[m], b3, acc3[m][n], 0, 0, 0);
      }
    }
    __syncthreads();
  }

  // epilogue: h = silu(a1)*a3 -> As (reused, plain [128][64]) -> coalesced store
#pragma unroll
  for (int m = 0; m < 4; ++m)
#pragma unroll
    for (int n = 0; n < 2; ++n)
#pragma unroll
      for (int q = 0; q < 4; ++q) {
        const float a1 = acc1[m][n][q];
        const float a3 = acc3[m][n][q];
        const float hv = a1 * a3 / (1.f + __expf(-a1));
        const int row = wm * 64 + m * 16 + lg * 4 + q;
        const int col = wn * 32 + n * 16 + lr;
        As[row * 64 + col] = f2bf(hv);
      }
  __syncthreads();
#pragma unroll
  for (int i = 0; i < 4; ++i) {
    const int idx = i * 256 + tid;
    const int r = idx >> 3, u = idx & 7;
    if (p0 + r < cnt)
      *(uint4*)(h_buf + ((size_t)(hbase + p0 + r) * HDIM + n0 + u * 8)) =
          *(const uint4*)&As[r * 64 + u * 8];
  }
}

// ---------------- GEMM2: part[pos] = h @ w2 (no atomics) ----------------
// table-dispatched. tile 128 pos x 128 d-cols x BK=64, per wave 64x64.
__global__ __launch_bounds__(256, 2) void moe_gemm2(
    const unsigned short* __restrict__ h_buf, const unsigned short* __restrict__ w2t,
    const int* __restrict__ counts, const int* __restrict__ offs,
    const int* __restrict__ t2e, const int* __restrict__ t2p,
    float* __restrict__ part)
{
  const int b = blockIdx.y;
  if (b >= offs[10]) return;
  const int e = t2e[b];
  const int p0 = t2p[b];
  const int cnt = counts[e * 32];
  const int n0 = blockIdx.x * 128;
  const int hbase = offs[e];

  __shared__ __align__(16) unsigned short Ah[128 * 64];
  __shared__ __align__(16) unsigned short Bw[128 * 64];

  const int tid = threadIdx.x;
  const int lane = tid & 63;
  const int wv = tid >> 6;
  const int wm = wv >> 1;
  const int wn = wv & 1;
  const int lr = lane & 15;
  const int lg = lane >> 4;
  const int l8 = lane >> 3;
  const int lu = lane & 7;
  const int aswz = (lu ^ l8) * 16;

  const unsigned short* asrc[4];
#pragma unroll
  for (int i = 0; i < 4; ++i) {
    const int p = p0 + wv * 32 + i * 8 + l8;
    const int hrow = hbase + ((p < cnt) ? p : 0);  // clamp to valid written row
    asrc[i] = h_buf + (size_t)hrow * HDIM;
  }
  const unsigned short* bsrc[4];
#pragma unroll
  for (int i = 0; i < 4; ++i) {
    const int n = n0 + wv * 32 + i * 8 + l8;
    bsrc[i] = w2t + (size_t)(e * DDIM + n) * HDIM;   // swizzle baked in storage
  }

  facc acc[4][4];
#pragma unroll
  for (int m = 0; m < 4; ++m)
#pragma unroll
    for (int n = 0; n < 4; ++n)
#pragma unroll
      for (int q = 0; q < 4; ++q) acc[m][n][q] = 0.f;

#pragma unroll 1
  for (int k0 = 0; k0 < HDIM; k0 += 64) {
#pragma unroll
    for (int i = 0; i < 4; ++i)
      gload16((const char*)asrc[i] + k0 * 2 + aswz, &Ah[(wv * 4 + i) * 512]);
#pragma unroll
    for (int i = 0; i < 4; ++i)
      gload16((const char*)bsrc[i] + k0 * 2 + lu * 16, &Bw[(wv * 4 + i) * 512]);
    __syncthreads();
#pragma unroll
    for (int ks = 0; ks < 2; ++ks) {
      bfrag a[4];
#pragma unroll
      for (int m = 0; m < 4; ++m) {
        const int r = wm * 64 + m * 16 + lr;
        const int u = (ks * 4 + lg) ^ (r & 7);
        a[m] = *(const bfrag*)&Ah[r * 64 + u * 8];
      }
#pragma unroll
      for (int n = 0; n < 4; ++n) {
        const int rb = wn * 64 + n * 16 + lr;
        const int u = (ks * 4 + lg) ^ (rb & 7);
        const bfrag bb = *(const bfrag*)&Bw[rb * 64 + u * 8];
#pragma unroll
        for (int m = 0; m < 4; ++m)
          acc[m][n] = __builtin_amdgcn_mfma_f32_16x16x32_bf16(a[m], bb, acc[m][n], 0, 0, 0);
      }
    }
    __syncthreads();
  }

#pragma unroll
  for (int m = 0; m < 4; ++m)
#pragma unroll
    for (int q = 0; q < 4; ++q) {
      const int p = p0 + wm * 64 + m * 16 + lg * 4 + q;
      if (p < cnt) {
        float* dst = part + (size_t)(hbase + p) * DDIM + n0 + wn * 64 + lr;
#pragma unroll
        for (int n = 0; n < 4; ++n)
          dst[n * 16] = acc[m][n][q];
      }
    }
}

// ---------------- combine: out[t] = wA*part[posA] + wB*part[posB] ----------------
__global__ __launch_bounds__(256) void combine_out(
    const float* __restrict__ part, const int* __restrict__ slotA,
    const int* __restrict__ slotB, const float* __restrict__ wt_list,
    const int* __restrict__ offs, float* __restrict__ out)
{
  const int t = blockIdx.x;
  const int sA = slotA[t], sB = slotB[t];
  const float wA = wt_list[sA], wB = wt_list[sB];
  const int pA = offs[sA >> 13] + (sA & (T_TOK - 1));
  const int pB = offs[sB >> 13] + (sB & (T_TOK - 1));
  const float* ra = part + (size_t)pA * DDIM;
  const float* rb = part + (size_t)pB * DDIM;
  float* o = out + (size_t)t * DDIM;
  const int i = threadIdx.x * 4;
  const float4 a = *(const float4*)(ra + i);
  const float4 b = *(const float4*)(rb + i);
  float4 r;
  r.x = wA * a.x + wB * b.x;
  r.y = wA * a.y + wB * b.y;
  r.z = wA * a.z + wB * b.z;
  r.w = wA * a.w + wB * b.w;
  *(float4*)(o + i) = r;
}

// ================= fallback path (previous verified kernels) =================
__global__ __launch_bounds__(64) void gate_topk_fb(
    const float* __restrict__ x, const float* __restrict__ gw,
    int* __restrict__ counts, int* __restrict__ tok_list,
    float* __restrict__ wt_list)
{
  const int t = blockIdx.x;
  const int lane = threadIdx.x;
  const float* xr = x + (size_t)t * DDIM;
  float p[NEXP];
#pragma unroll
  for (int e = 0; e < NEXP; ++e) p[e] = 0.f;
#pragma unroll 4
  for (int i = 0; i < DDIM / 64; ++i) {
    const int d = i * 64 + lane;
    const float xv = xr[d];
    const float4 g0 = *(const float4*)(gw + (size_t)d * NEXP);
    const float4 g1 = *(const float4*)(gw + (size_t)d * NEXP + 4);
    p[0] += xv * g0.x; p[1] += xv * g0.y; p[2] += xv * g0.z; p[3] += xv * g0.w;
    p[4] += xv * g1.x; p[5] += xv * g1.y; p[6] += xv * g1.z; p[7] += xv * g1.w;
  }
#pragma unroll
  for (int off = 32; off > 0; off >>= 1) {
#pragma unroll
    for (int e = 0; e < NEXP; ++e) p[e] += __shfl_down(p[e], off);
  }
  if (lane == 0) {
    int i1 = 0; float v1 = p[0];
#pragma unroll
    for (int e = 1; e < NEXP; ++e) if (p[e] > v1) { v1 = p[e]; i1 = e; }
    int i2 = -1; float v2 = -3.4e38f;
#pragma unroll
    for (int e = 0; e < NEXP; ++e) if (e != i1 && p[e] > v2) { v2 = p[e]; i2 = e; }
    const float w0 = 1.f / (1.f + __expf(v2 - v1));
    int q1 = atomicAdd(&counts[i1 * 32], 1);
    tok_list[i1 * T_TOK + q1] = t;
    wt_list[i1 * T_TOK + q1] = w0;
    int q2 = atomicAdd(&counts[i2 * 32], 1);
    tok_list[i2 * T_TOK + q2] = t;
    wt_list[i2 * T_TOK + q2] = 1.f - w0;
  }
}

__global__ __launch_bounds__(256) void moe_gemm1_fb(
    const float* __restrict__ x, const float* __restrict__ w1,
    const float* __restrict__ w3, const int* __restrict__ counts,
    const int* __restrict__ tok_list, unsigned short* __restrict__ h_buf,
    int e)
{
  const int cnt = counts[e * 32];
  const int p0 = blockIdx.y * 64;
  if (p0 >= cnt) return;
  const int n0 = blockIdx.x * 64;

  __shared__ unsigned short As[64][40];
  __shared__ unsigned short B1s[64][40];
  __shared__ unsigned short B3s[64][40];

  const int tid = threadIdx.x;
  const int lane = tid & 63;
  const int wv = tid >> 6;

  const float* w1e = w1 + (size_t)e * DDIM * HDIM;
  const float* w3e = w3 + (size_t)e * DDIM * HDIM;
  const int* tl = tok_list + e * T_TOK;

  const int arow = tid >> 2;
  const int akseg = (tid & 3) * 8;
  int tok = -1;
  if (p0 + arow < cnt) tok = tl[p0 + arow];

  const int bk = tid >> 3;
  const int bn4 = (tid & 7) * 4;

  facc acc1[4], acc3[4];
#pragma unroll
  for (int i = 0; i < 4; ++i)
#pragma unroll
    for (int j = 0; j < 4; ++j) { acc1[i][j] = 0.f; acc3[i][j] = 0.f; }

  const int mrow = wv * 16 + (lane & 15);
  const int kq = (lane >> 4) * 8;

  for (int k0 = 0; k0 < DDIM; k0 += 32) {
    {
      union { unsigned short s[8]; uint4 v; } tmp;
      if (tok >= 0) {
        const float* src = x + (size_t)tok * DDIM + k0 + akseg;
        const float4 f0 = *(const float4*)(src);
        const float4 f1 = *(const float4*)(src + 4);
        tmp.s[0]=f2bf(f0.x); tmp.s[1]=f2bf(f0.y); tmp.s[2]=f2bf(f0.z); tmp.s[3]=f2bf(f0.w);
        tmp.s[4]=f2bf(f1.x); tmp.s[5]=f2bf(f1.y); tmp.s[6]=f2bf(f1.z); tmp.s[7]=f2bf(f1.w);
      } else {
        tmp.v = make_uint4(0u, 0u, 0u, 0u);
      }
      *(uint4*)&As[arow][akseg] = tmp.v;
    }
#pragma unroll
    for (int pass = 0; pass < 2; ++pass) {
      const int n = bn4 + pass * 32;
      const float4 f1v = *(const float4*)(w1e + (size_t)(k0 + bk) * HDIM + n0 + n);
      B1s[n + 0][bk] = f2bf(f1v.x);
      B1s[n + 1][bk] = f2bf(f1v.y);
      B1s[n + 2][bk] = f2bf(f1v.z);
      B1s[n + 3][bk] = f2bf(f1v.w);
      const float4 f3v = *(const float4*)(w3e + (size_t)(k0 + bk) * HDIM + n0 + n);
      B3s[n + 0][bk] = f2bf(f3v.x);
      B3s[n + 1][bk] = f2bf(f3v.y);
      B3s[n + 2][bk] = f2bf(f3v.z);
      B3s[n + 3][bk] = f2bf(f3v.w);
    }
    __syncthreads();
    const bfrag a = *(const bfrag*)&As[mrow][kq];
#pragma unroll
    for (int nt = 0; nt < 4; ++nt) {
      const bfrag b1 = *(const bfrag*)&B1s[nt * 16 + (lane & 15)][kq];
      acc1[nt] = __builtin_amdgcn_mfma_f32_16x16x32_bf16(a, b1, acc1[nt], 0, 0, 0);
      const bfrag b3 = *(const bfrag*)&B3s[nt * 16 + (lane & 15)][kq];
      acc3[nt] = __builtin_amdgcn_mfma_f32_16x16x32_bf16(a, b3, acc3[nt], 0, 0, 0);
    }
    __syncthreads();
  }
  const int rbase = p0 + wv * 16 + ((lane >> 4) * 4);
  const int cbase = n0 + (lane & 15);
#pragma unroll
  for (int r = 0; r < 4; ++r) {
    const int p = rbase + r;
    if (p < cnt) {
      unsigned short* dst = h_buf + (size_t)p * HDIM + cbase;
#pragma unroll
      for (int nt = 0; nt < 4; ++nt) {
        const float a1 = acc1[nt][r];
        const float a3 = acc3[nt][r];
        const float hv = a1 * a3 / (1.f + __expf(-a1));
        dst[nt * 16] = f2bf(hv);
      }
    }
  }
}

__global__ __launch_bounds__(256) void moe_gemm2_fb(
    const unsigned short* __restrict__ h_buf, const float* __restrict__ w2,
    const int* __restrict__ counts, const int* __restrict__ tok_list,
    const float* __restrict__ wt_list, float* __restrict__ out, int e)
{
  const int cnt = counts[e * 32];
  const int p0 = blockIdx.y * 64;
  if (p0 >= cnt) return;
  const int n0 = blockIdx.x * 64;

  __shared__ unsigned short As[64][40];
  __shared__ unsigned short Bs[64][40];

  const int tid = threadIdx.x;
  const int lane = tid & 63;
  const int wv = tid >> 6;

  const float* w2e = w2 + (size_t)e * HDIM * DDIM;
  const int* tl = tok_list + e * T_TOK;
  const float* wl = wt_list + e * T_TOK;

  const int arow = tid >> 2;
  const int akseg = (tid & 3) * 8;
  const bool avalid = (p0 + arow < cnt);

  const int bk = tid >> 3;
  const int bn4 = (tid & 7) * 4;

  facc acc[4];
#pragma unroll
  for (int i = 0; i < 4; ++i)
#pragma unroll
    for (int j = 0; j < 4; ++j) acc[i][j] = 0.f;

  const int mrow = wv * 16 + (lane & 15);
  const int kq = (lane >> 4) * 8;

  for (int k0 = 0; k0 < HDIM; k0 += 32) {
    if (avalid) {
      *(uint4*)&As[arow][akseg] =
          *(const uint4*)(h_buf + (size_t)(p0 + arow) * HDIM + k0 + akseg);
    } else {
      *(uint4*)&As[arow][akseg] = make_uint4(0u, 0u, 0u, 0u);
    }
#pragma unroll
    for (int pass = 0; pass < 2; ++pass) {
      const int n = bn4 + pass * 32;
      const float4 f = *(const float4*)(w2e + (size_t)(k0 + bk) * DDIM + n0 + n);
      Bs[n + 0][bk] = f2bf(f.x);
      Bs[n + 1][bk] = f2bf(f.y);
      Bs[n + 2][bk] = f2bf(f.z);
      Bs[n + 3][bk] = f2bf(f.w);
    }
    __syncthreads();
    const bfrag a = *(const bfrag*)&As[mrow][kq];
#pragma unroll
    for (int nt = 0; nt < 4; ++nt) {
      const bfrag b = *(const bfrag*)&Bs[nt * 16 + (lane & 15)][kq];
      acc[nt] = __builtin_amdgcn_mfma_f32_16x16x32_bf16(a, b, acc[nt], 0, 0, 0);
    }
    __syncthreads();
  }
  const int rbase = p0 + wv * 16 + ((lane >> 4) * 4);
  const int cbase = n0 + (lane & 15);
#pragma unroll
  for (int r = 0; r < 4; ++r) {
    const int p = rbase + r;
    if (p < cnt) {
      const int tok = tl[p];
      const float wt = wl[p];
      float* dst = out + (size_t)tok * DDIM + cbase;
#pragma unroll
      for (int nt = 0; nt < 4; ++nt) {
        atomicAdd(dst + nt * 16, acc[nt][r] * wt);
      }
    }
  }
}

__global__ void ws_too_small(float* out, int n) {
  int i = blockIdx.x * 256 + threadIdx.x;
  if (i < n) out[i] = 1.0e6f;   // sentinel: workspace shortage, not a math bug
}

extern "C" void kernel_launch(void* const* d_in, const int* in_sizes, int n_in,
                              void* d_out, int out_size, void* d_ws, size_t ws_size,
                              hipStream_t stream) {
  // setup_inputs dict order: x, gate_w, w1, w3, w2
  const float* x  = (const float*)d_in[0];
  const float* gw = (const float*)d_in[1];
  const float* w1 = (const float*)d_in[2];
  const float* w3 = (const float*)d_in[3];
  const float* w2 = (const float*)d_in[4];
  float* out = (float*)d_out;

  // ---- new-path workspace layout (bf16 weights pre-transposed+swizzled) ----
  // [0,1024): counts (8 ints, 128B apart); [1024,2048): offs (incl. blk counts)
  // [2048,4608): dispatch tables t1e/t1p/t2e/t2p, 640B (160 ints) each
  const size_t off_tok = 5120;
  const size_t off_wt  = off_tok + (size_t)NEXP * T_TOK * 4;
  const size_t off_sA  = off_wt + (size_t)NEXP * T_TOK * 4;      // slotA [T_TOK]
  const size_t off_sB  = off_sA + (size_t)T_TOK * 4;             // slotB [T_TOK]
  const size_t off_xb  = off_sB + (size_t)T_TOK * 4;
  const size_t off_w1t = off_xb + (size_t)T_TOK * DDIM * 2;
  const size_t off_w3t = off_w1t + (size_t)NEXP * DDIM * HDIM * 2;
  const size_t off_w2t = off_w3t + (size_t)NEXP * DDIM * HDIM * 2;
  const size_t off_h   = off_w2t + (size_t)NEXP * HDIM * DDIM * 2;
  const size_t need    = off_h + (size_t)(2 * T_TOK) * HDIM * 2; // sum(cnt)=2*T_TOK
  // part[2*T_TOK][DDIM] fp32 (64 MB) ALIASES w1t+w3t (100 MB, dead after gemm1)
  const size_t off_part = off_w1t;

  if (ws_size >= need) {
    int* counts = (int*)d_ws;
    int* offs = (int*)((char*)d_ws + 1024);
    int* t1e = (int*)((char*)d_ws + 2048);
    int* t1p = (int*)((char*)d_ws + 2688);
    int* t2e = (int*)((char*)d_ws + 3328);
    int* t2p = (int*)((char*)d_ws + 3968);
    int* tok_list = (int*)((char*)d_ws + off_tok);
    float* wt_list = (float*)((char*)d_ws + off_wt);
    int* slotA = (int*)((char*)d_ws + off_sA);
    int* slotB = (int*)((char*)d_ws + off_sB);
    unsigned short* xb  = (unsigned short*)((char*)d_ws + off_xb);
    unsigned short* w1t = (unsigned short*)((char*)d_ws + off_w1t);
    unsigned short* w3t = (unsigned short*)((char*)d_ws + off_w3t);
    unsigned short* w2t = (unsigned short*)((char*)d_ws + off_w2t);
    unsigned short* h_buf = (unsigned short*)((char*)d_ws + off_h);
    float* part = (float*)((char*)d_ws + off_part);

    hipMemsetAsync(counts, 0, 1024, stream);

    convert_gate<<<9216 + T_TOK / 4, 256, 0, stream>>>(
        w1, w3, w2, w1t, w3t, w2t, x, gw, counts, tok_list, wt_list,
        slotA, slotB, xb);
    calc_offs<<<1, 1, 0, stream>>>(counts, offs, t1e, t1p, t2e, t2p);
    moe_gemm1<<<dim3(HDIM / 64, 144), 256, 0, stream>>>(
        xb, w1t, w3t, counts, offs, t1e, t1p, tok_list, h_buf);
    moe_gemm2<<<dim3(DDIM / 128, 144), 256, 0, stream>>>(
        h_buf, w2t, counts, offs, t2e, t2p, part);
    combine_out<<<T_TOK, 256, 0, stream>>>(part, slotA, slotB, wt_list, offs, out);
    return;
  }

  // ---- fallback: previous verified path (fp32 weights, per-expert loop) ----
  const size_t fb_off_tok = 1024;
  const size_t fb_off_wt  = fb_off_tok + (size_t)NEXP * T_TOK * 4;
  const size_t fb_off_h   = fb_off_wt + (size_t)NEXP * T_TOK * 4;
  const size_t fb_need    = fb_off_h + (size_t)T_TOK * HDIM * 2;
  if (ws_size < fb_need) {
    ws_too_small<<<(out_size + 255) / 256, 256, 0, stream>>>(out, out_size);
    return;
  }
  int* counts = (int*)d_ws;
  int* tok_list = (int*)((char*)d_ws + fb_off_tok);
  float* wt_list = (float*)((char*)d_ws + fb_off_wt);
  unsigned short* h_buf = (unsigned short*)((char*)d_ws + fb_off_h);

  hipMemsetAsync(counts, 0, 1024, stream);
  hipMemsetAsync(out, 0, (size_t)out_size * sizeof(float), stream);

  gate_topk_fb<<<T_TOK, 64, 0, stream>>>(x, gw, counts, tok_list, wt_list);
  for (int e = 0; e < NEXP; ++e) {
    moe_gemm1_fb<<<dim3(HDIM / 64, T_TOK / 64), 256, 0, stream>>>(
        x, w1, w3, counts, tok_list, h_buf, e);
    moe_gemm2_fb<<<dim3(DDIM / 64, T_TOK / 64), 256, 0, stream>>>(
        h_buf, w2, counts, tok_list, wt_list, out, e);
  }
}